// Round 18
// baseline (799.267 us; speedup 1.0000x reference)
//
#include <hip/hip_runtime.h>
#include <hip/hip_bf16.h>

#define NNODES 100000
#define NEDGES 1600000
#define DIM    128
#define NF     64
#define NFP    65                          // padded LDS row stride in floats (260B)
#define NG     50

#define BSH    8                           // bucket = dst >> 8 (256 nodes/bucket)
#define BNODES 256
#define NBKT   ((NNODES + 255) >> 8)       // 391 buckets
#define CHK    8192                        // bscatter edges/block (dense chunks)
#define NCHK   ((NEDGES + CHK - 1) / CHK)  // 196 blocks

#define NBIN   16385                       // table rows: bin = round(d * 16384/5)

constexpr float F_CUTOFF = 5.0f;
constexpr float F_DELTA  = F_CUTOFF / (NG - 1);
constexpr float F_COEFF  = -0.5f / (F_DELTA * F_DELTA);
constexpr float F_PI     = 3.14159265358979323846f;
constexpr float TSCALE   = 16384.0f / F_CUTOFF;

typedef __attribute__((ext_vector_type(8))) short short8v;
typedef __attribute__((ext_vector_type(4))) float f32x4;

__device__ inline unsigned short f2bf(float x) {
  __hip_bfloat16 h = __float2bfloat16(x);
  return *reinterpret_cast<unsigned short*>(&h);
}
__device__ inline unsigned pkbf(float a, float b) {
  float2 f2; f2.x = a; f2.y = b;
  __hip_bfloat162 h2 = __float22bfloat162_rn(f2);
  return *reinterpret_cast<unsigned*>(&h2);
}
__device__ inline float bf2f(unsigned int lo16) {
  return __uint_as_float(lo16 << 16);
}

// ---------------- kernel 1 (MFMA): h[n][f] = sum_k x[n][k] * lin1_w[f][k]  (bf16 out) ----------------
__global__ __launch_bounds__(256, 2) void k_lin1_mfma(
    const float* __restrict__ x, const float* __restrict__ w1,
    unsigned short* __restrict__ h) {
  const int wave = threadIdx.x >> 6, lane = threadIdx.x & 63;
  const int lo = lane & 15, g = lane >> 4;

  short8v B[4][4];
#pragma unroll
  for (int t = 0; t < 4; ++t) {
    const int j = (t >> 1) * 32 + 2 * lo + (t & 1);
#pragma unroll
    for (int s = 0; s < 4; ++s) {
      union { short8v v; unsigned u[4]; } bu;
      const float* wr = w1 + j * DIM + s * 32 + g * 8;
#pragma unroll
      for (int p = 0; p < 4; ++p)
        bu.u[p] = pkbf(wr[2 * p], wr[2 * p + 1]);
      B[t][s] = bu.v;
    }
  }

  const int nIter = NNODES / 16;   // 6250
  for (int it = blockIdx.x * 4 + wave; it < nIter; it += gridDim.x * 4) {
    const int n0 = it * 16;
    short8v A[4];
#pragma unroll
    for (int s = 0; s < 4; ++s) {
      const float4 va = *(const float4*)&x[(size_t)(n0 + lo) * DIM + s * 32 + g * 8];
      const float4 vb = *(const float4*)&x[(size_t)(n0 + lo) * DIM + s * 32 + g * 8 + 4];
      union { short8v v; unsigned u[4]; } au;
      au.u[0] = pkbf(va.x, va.y);
      au.u[1] = pkbf(va.z, va.w);
      au.u[2] = pkbf(vb.x, vb.y);
      au.u[3] = pkbf(vb.z, vb.w);
      A[s] = au.v;
    }
    f32x4 acc[4];
#pragma unroll
    for (int t = 0; t < 4; ++t) {
      f32x4 z = {0.f, 0.f, 0.f, 0.f};
      z = __builtin_amdgcn_mfma_f32_16x16x32_bf16(A[0], B[t][0], z, 0, 0, 0);
      z = __builtin_amdgcn_mfma_f32_16x16x32_bf16(A[1], B[t][1], z, 0, 0, 0);
      z = __builtin_amdgcn_mfma_f32_16x16x32_bf16(A[2], B[t][2], z, 0, 0, 0);
      z = __builtin_amdgcn_mfma_f32_16x16x32_bf16(A[3], B[t][3], z, 0, 0, 0);
      acc[t] = z;
    }
#pragma unroll
    for (int r = 0; r < 4; ++r) {
      unsigned short* hp = h + (size_t)(n0 + g * 4 + r) * NF + 2 * lo;
      *(unsigned*)(hp)      = pkbf(acc[0][r], acc[1][r]);
      *(unsigned*)(hp + 32) = pkbf(acc[2][r], acc[3][r]);
    }
  }
}

// ---------------- edge-filter table ----------------
__global__ __launch_bounds__(256) void k_table(
    const float* __restrict__ w1, const float* __restrict__ b1,
    const float* __restrict__ w2, const float* __restrict__ b2,
    unsigned short* __restrict__ tab) {
  __shared__ float ssm[4][56];
  __shared__ float sh1[4][64];
  const int wave = threadIdx.x >> 6, lane = threadIdx.x & 63;
  const int wid = blockIdx.x * 4 + wave;
  const float b1v = b1[lane], b2v = b2[lane];
  for (int bin = wid; bin < NBIN; bin += 1024) {
    const float d = (float)bin * (F_CUTOFF / 16384.0f);
    if (lane < NG) {
      const float t0 = d - (float)lane * F_DELTA;
      ssm[wave][lane] = __expf(F_COEFF * t0 * t0);
    }
    float h1 = b1v;
#pragma unroll
    for (int gg = 0; gg < NG; ++gg)
      h1 = fmaf(ssm[wave][gg], w1[lane * NG + gg], h1);
    sh1[wave][lane] = fmaxf(h1, 0.f);
    float wv = b2v;
#pragma unroll
    for (int f = 0; f < NF; ++f)
      wv = fmaf(sh1[wave][f], w2[lane * NF + f], wv);
    const float C = 0.5f * (__cosf(d * (F_PI / F_CUTOFF)) + 1.0f);
    tab[(size_t)bin * NF + lane] = f2bf(wv * C);
  }
}

// ---------------- bucket histogram: 196 blocks x 1024 threads ----------------
__global__ __launch_bounds__(1024) void k_bhist(
    const int* __restrict__ ei, int* __restrict__ gcnt) {
  __shared__ int lcnt[NBKT];
  for (int i = threadIdx.x; i < NBKT; i += 1024) lcnt[i] = 0;
  __syncthreads();
  const int base = blockIdx.x * CHK;
  for (int i = threadIdx.x; i < CHK; i += 1024) {
    const int e = base + i;
    if (e < NEDGES) atomicAdd(&lcnt[ei[NEDGES + e] >> BSH], 1);
  }
  __syncthreads();
  for (int i = threadIdx.x; i < NBKT; i += 1024)
    if (lcnt[i]) atomicAdd(&gcnt[i], lcnt[i]);
}

// ---------------- scan 391 bucket totals -> boff (exclusive) + cursor copy ----------------
__global__ __launch_bounds__(512) void k_bscan(
    const int* __restrict__ gcnt, int* __restrict__ boff, int* __restrict__ bcur) {
  __shared__ int sb[512];
  const int t = threadIdx.x;
  const int v = (t < NBKT) ? gcnt[t] : 0;
  sb[t] = v;
  __syncthreads();
  for (int off = 1; off < 512; off <<= 1) {
    const int xv = (t >= off) ? sb[t - off] : 0;
    __syncthreads();
    sb[t] += xv;
    __syncthreads();
  }
  if (t <= NBKT) {
    const int ex = sb[t] - v;
    boff[t] = ex;
    if (t < NBKT) bcur[t] = ex;
  }
}

// ---------------- bucket-scatter: 196 x 1024, reg-cached edges, packed 8B records ----------------
// record: x = src | (bin<<17)  (src<2^17, bin<=16384<2^15), y = dst
__global__ __launch_bounds__(1024) void k_bscatter(
    const int* __restrict__ ei, const float* __restrict__ ea,
    int* __restrict__ bcur, int2* __restrict__ spack) {
  __shared__ int lcnt[NBKT];
  __shared__ int lcur[NBKT];
  const int t = threadIdx.x;
  for (int i = t; i < NBKT; i += 1024) lcnt[i] = 0;
  __syncthreads();
  const int base = blockIdx.x * CHK;
  int dsts[8], srcs[8]; float eav[8];
#pragma unroll
  for (int k = 0; k < 8; ++k) {
    const int e = base + t + k * 1024;
    const bool v = e < NEDGES;
    dsts[k] = v ? ei[NEDGES + e] : -1;
    srcs[k] = v ? ei[e] : 0;
    eav[k]  = v ? ea[e] : 0.f;
    if (v) atomicAdd(&lcnt[dsts[k] >> BSH], 1);
  }
  __syncthreads();
  for (int i = t; i < NBKT; i += 1024)
    lcur[i] = lcnt[i] ? atomicAdd(&bcur[i], lcnt[i]) : 0;
  __syncthreads();
#pragma unroll
  for (int k = 0; k < 8; ++k) {
    if (dsts[k] >= 0) {
      const int pos = atomicAdd(&lcur[dsts[k] >> BSH], 1);
      const float dcl = fminf(fmaxf(eav[k], 0.f), F_CUTOFF);
      int bn = (int)(dcl * TSCALE + 0.5f);
      bn = (bn > 16384) ? 16384 : bn;
      int2 r; r.x = srcs[k] | (bn << 17); r.y = dsts[k];
      spack[pos] = r;
    }
  }
}

// ---------------- fused edge+aggregate: one block per bucket, LDS f32 accumulator, ILP=4 ----------------
// r17 lesson: the 691us across r15-r17 was memory-LATENCY bound, not atomic-path bound —
// 1 edge in flight per group vs edge_tab's 4 (16x MLP deficit matched the exact 16x slowdown).
// This version: each 16-lane group processes 4 edges/iter (eb, eb+64, eb+128, eb+192),
// issuing all 8 hbf gathers + 8 table loads before consuming. Tail edges masked by m*=0
// (ds_add of 0.0 to row 0 is harmless). ds_add_f32 via inline asm (r17-verified correct).
__global__ __launch_bounds__(1024) void k_edge_lds(
    const int2* __restrict__ spack, const int* __restrict__ boff,
    const unsigned short* __restrict__ hbf, const unsigned* __restrict__ tab,
    unsigned short* __restrict__ agg) {
  __shared__ float sagg[BNODES * NFP];   // 66560 B
  const int b = blockIdx.x;
  const int t = threadIdx.x;
  const int lo  = t & 15;
  const int grp = t >> 4;    // 0..63
  const int s0 = boff[b], s1 = boff[b + 1];
  const int nodeBase = b << BSH;
  const unsigned sbase = (unsigned)(size_t)&sagg[0];

  for (int i = t; i < BNODES * NFP; i += 1024) sagg[i] = 0.f;
  __syncthreads();

  int eb = s0 + grp;
  int2 q[4];
#pragma unroll
  for (int j = 0; j < 4; ++j)
    if (eb + j * 64 < s1) q[j] = spack[eb + j * 64];

  while (eb < s1) {
    int2 c[4];
#pragma unroll
    for (int j = 0; j < 4; ++j) c[j] = q[j];
    const int ebn = eb + 256;
#pragma unroll
    for (int j = 0; j < 4; ++j)
      if (ebn + j * 64 < s1) q[j] = spack[ebn + j * 64];

    // decode + mask
    int srcv[4], locv[4]; unsigned bnv[4]; float msk[4];
#pragma unroll
    for (int j = 0; j < 4; ++j) {
      const bool val = (eb + j * 64) < s1;
      srcv[j] = val ? (c[j].x & 0x1FFFF) : 0;
      bnv[j]  = val ? ((unsigned)c[j].x >> 17) : 0;
      locv[j] = val ? (c[j].y - nodeBase) : 0;
      msk[j]  = val ? 1.f : 0.f;
    }

    // issue ALL gathers (8 hbf + 8 tab lines in flight per group)
    unsigned hp0[4], hp1[4], tw0[4], tw1[4];
#pragma unroll
    for (int j = 0; j < 4; ++j) {
      const unsigned short* hs = hbf + (size_t)srcv[j] * NF + 2 * lo;
      hp0[j] = *(const unsigned*)(hs);
      hp1[j] = *(const unsigned*)(hs + 32);
    }
#pragma unroll
    for (int j = 0; j < 4; ++j) {
      const unsigned* trow = tab + (size_t)bnv[j] * (NF / 2);
      tw0[j] = trow[lo];
      tw1[j] = trow[16 + lo];
    }

#pragma unroll
    for (int j = 0; j < 4; ++j) {
      const float m0 = bf2f(hp0[j] & 0xffffu) * bf2f(tw0[j] & 0xffffu) * msk[j];
      const float m1 = bf2f(hp0[j] >> 16)     * bf2f(tw0[j] >> 16)     * msk[j];
      const float m2 = bf2f(hp1[j] & 0xffffu) * bf2f(tw1[j] & 0xffffu) * msk[j];
      const float m3 = bf2f(hp1[j] >> 16)     * bf2f(tw1[j] >> 16)     * msk[j];
      const unsigned a = sbase + (unsigned)(locv[j] * (NFP * 4) + lo * 8);
      asm volatile("ds_add_f32 %0, %1"            :: "v"(a), "v"(m0) : "memory");
      asm volatile("ds_add_f32 %0, %1 offset:4"   :: "v"(a), "v"(m1) : "memory");
      asm volatile("ds_add_f32 %0, %1 offset:128" :: "v"(a), "v"(m2) : "memory");
      asm volatile("ds_add_f32 %0, %1 offset:132" :: "v"(a), "v"(m3) : "memory");
    }
    eb = ebn;
  }
  asm volatile("s_waitcnt lgkmcnt(0)" ::: "memory");
  __syncthreads();

  // epilogue: dense bf16 write
  unsigned* aggw = (unsigned*)(agg + (size_t)nodeBase * NF);
  for (int i = t; i < BNODES * NF / 2; i += 1024) {
    const int n  = i >> 5;
    const int f2 = i & 31;
    if (nodeBase + n < NNODES)
      aggw[i] = pkbf(sagg[n * NFP + 2 * f2], sagg[n * NFP + 2 * f2 + 1]);
  }
}

// ---------------- kernel 3: out[n][d] = x[n][d] + relu(b[d] + agg[n,:] . lin2_w[d,:]) ----------------
__global__ __launch_bounds__(256) void k_out(
    const float* __restrict__ x, const unsigned short* __restrict__ agg,
    const float* __restrict__ w2, const float* __restrict__ b,
    float* __restrict__ out) {
  __shared__ __align__(16) float sw[DIM][NF + 4];
  __shared__ __align__(16) float sa[4][4][NF];
  for (int i = threadIdx.x; i < DIM * NF; i += 256)
    sw[i >> 6][i & 63] = w2[i];
  __syncthreads();
  const int wave = threadIdx.x >> 6, lane = threadIdx.x & 63;
  const float bias0 = b[lane], bias1 = b[lane + 64];
  const int nIter = NNODES / 4;
  for (int it = blockIdx.x * 4 + wave; it < nIter; it += gridDim.x * 4) {
    const int n0 = it * 4;
#pragma unroll
    for (int i = 0; i < 4; ++i)
      sa[wave][i][lane] = bf2f((unsigned)agg[(size_t)(n0 + i) * NF + lane]);
    float acc[8];
#pragma unroll
    for (int i = 0; i < 4; ++i) { acc[2 * i] = bias0; acc[2 * i + 1] = bias1; }
#pragma unroll
    for (int j4 = 0; j4 < NF / 4; ++j4) {
      const float4 wv0 = *(const float4*)&sw[lane][j4 * 4];
      const float4 wv1 = *(const float4*)&sw[lane + 64][j4 * 4];
#pragma unroll
      for (int i = 0; i < 4; ++i) {
        const float4 av = *(const float4*)&sa[wave][i][j4 * 4];
        acc[2 * i]     = fmaf(wv0.x, av.x, acc[2 * i]);
        acc[2 * i]     = fmaf(wv0.y, av.y, acc[2 * i]);
        acc[2 * i]     = fmaf(wv0.z, av.z, acc[2 * i]);
        acc[2 * i]     = fmaf(wv0.w, av.w, acc[2 * i]);
        acc[2 * i + 1] = fmaf(wv1.x, av.x, acc[2 * i + 1]);
        acc[2 * i + 1] = fmaf(wv1.y, av.y, acc[2 * i + 1]);
        acc[2 * i + 1] = fmaf(wv1.z, av.z, acc[2 * i + 1]);
        acc[2 * i + 1] = fmaf(wv1.w, av.w, acc[2 * i + 1]);
      }
    }
#pragma unroll
    for (int i = 0; i < 4; ++i) {
      const size_t base = (size_t)(n0 + i) * DIM;
      out[base + lane]      = x[base + lane]      + fmaxf(acc[2 * i],     0.f);
      out[base + 64 + lane] = x[base + 64 + lane] + fmaxf(acc[2 * i + 1], 0.f);
    }
  }
}

extern "C" void kernel_launch(void* const* d_in, const int* in_sizes, int n_in,
                              void* d_out, int out_size, void* d_ws, size_t ws_size,
                              hipStream_t stream) {
  const float* x   = (const float*)d_in[0];
  const int*   ei  = (const int*)  d_in[1];
  const float* ea  = (const float*)d_in[3];   // edge_attr == edge_weight (same dist)
  const float* l1w = (const float*)d_in[4];
  const float* l2w = (const float*)d_in[5];
  const float* l2b = (const float*)d_in[6];
  const float* e1w = (const float*)d_in[7];
  const float* e1b = (const float*)d_in[8];
  const float* e2w = (const float*)d_in[9];
  const float* e2b = (const float*)d_in[10];
  float* out = (float*)d_out;

  // ws carve: hbf 12.8 + agg 12.8 + spack 12.8 + table 2.1 + small ≈ 41 MB
  char* p = (char*)d_ws;
  unsigned short* hbf = (unsigned short*)p; p += (size_t)NNODES * NF * 2;
  unsigned short* agg = (unsigned short*)p; p += (size_t)NNODES * NF * 2;
  int2* spack = (int2*)p;                   p += (size_t)NEDGES * 8;
  unsigned short* tab = (unsigned short*)p; p += (size_t)16512 * NF * 2;
  int*  gcnt  = (int*)p;                    p += 1024 * 4;
  int*  boff  = (int*)p;                    p += 1024 * 4;
  int*  bcur  = (int*)p;                    p += 1024 * 4;

  hipMemsetAsync(gcnt, 0, 1024 * sizeof(int), stream);

  k_table    <<<256, 256, 0, stream>>>(e1w, e1b, e2w, e2b, tab);
  k_lin1_mfma<<<512, 256, 0, stream>>>(x, l1w, hbf);
  k_bhist    <<<NCHK, 1024, 0, stream>>>(ei, gcnt);
  k_bscan    <<<1, 512, 0, stream>>>(gcnt, boff, bcur);
  k_bscatter <<<NCHK, 1024, 0, stream>>>(ei, ea, bcur, spack);
  k_edge_lds <<<NBKT, 1024, 0, stream>>>(spack, boff, hbf, (const unsigned*)tab, agg);
  k_out      <<<2048, 256, 0, stream>>>(x, agg, l2w, l2b, out);
}

// Round 19
// 161.132 us; speedup vs baseline: 4.9603x; 4.9603x over previous
//
#include <hip/hip_runtime.h>
#include <hip/hip_bf16.h>

#define NNODES 100000
#define NEDGES 1600000
#define DIM    128
#define NF     64
#define NG     50
#define EPG    52        // edges per 16-lane group chunk (13 iters x 4)
#define EPW    208       // edges per wave (4 groups)
#define NWAVES 8192      // 2048 blocks x 4 waves
#define EPTOT  1703936   // NWAVES * EPW  (>= NEDGES, OOB slots masked)

#define BSH    9                           // bucket = dst >> 9 (512 nodes/bucket) — proven r10/r12/r14
#define NBKT   ((NNODES + 511) >> 9)       // 196 buckets
#define CHK    8192                        // edges/block in bucket passes (dense 42-edge chunks)
#define NCHK   ((NEDGES + CHK - 1) / CHK)  // 196 blocks

#define NBIN   16385                       // table rows: bin = round(d * 16384/5)

constexpr float F_CUTOFF = 5.0f;
constexpr float F_DELTA  = F_CUTOFF / (NG - 1);
constexpr float F_COEFF  = -0.5f / (F_DELTA * F_DELTA);
constexpr float F_PI     = 3.14159265358979323846f;
constexpr float TSCALE   = 16384.0f / F_CUTOFF;

typedef __attribute__((ext_vector_type(8))) short short8v;
typedef __attribute__((ext_vector_type(4))) float f32x4;

__device__ inline unsigned short f2bf(float x) {
  __hip_bfloat16 h = __float2bfloat16(x);
  return *reinterpret_cast<unsigned short*>(&h);
}
__device__ inline unsigned pkbf(float a, float b) {
  float2 f2; f2.x = a; f2.y = b;
  __hip_bfloat162 h2 = __float22bfloat162_rn(f2);
  return *reinterpret_cast<unsigned*>(&h2);
}
__device__ inline float bf2f(unsigned int lo16) {
  return __uint_as_float(lo16 << 16);
}

// ---------------- kernel 1 (MFMA): h[n][f] = sum_k x[n][k] * lin1_w[f][k]  (bf16 out) ----------------
// launch_bounds(256,2): VGPR cap keeps the 64-VGPR B fragments resident (r6/r13 lesson).
__global__ __launch_bounds__(256, 2) void k_lin1_mfma(
    const float* __restrict__ x, const float* __restrict__ w1,
    unsigned short* __restrict__ h) {
  const int wave = threadIdx.x >> 6, lane = threadIdx.x & 63;
  const int lo = lane & 15, g = lane >> 4;

  short8v B[4][4];
#pragma unroll
  for (int t = 0; t < 4; ++t) {
    const int j = (t >> 1) * 32 + 2 * lo + (t & 1);
#pragma unroll
    for (int s = 0; s < 4; ++s) {
      union { short8v v; unsigned u[4]; } bu;
      const float* wr = w1 + j * DIM + s * 32 + g * 8;
#pragma unroll
      for (int p = 0; p < 4; ++p)
        bu.u[p] = pkbf(wr[2 * p], wr[2 * p + 1]);
      B[t][s] = bu.v;
    }
  }

  const int nIter = NNODES / 16;   // 6250
  for (int it = blockIdx.x * 4 + wave; it < nIter; it += gridDim.x * 4) {
    const int n0 = it * 16;
    short8v A[4];
#pragma unroll
    for (int s = 0; s < 4; ++s) {
      const float4 va = *(const float4*)&x[(size_t)(n0 + lo) * DIM + s * 32 + g * 8];
      const float4 vb = *(const float4*)&x[(size_t)(n0 + lo) * DIM + s * 32 + g * 8 + 4];
      union { short8v v; unsigned u[4]; } au;
      au.u[0] = pkbf(va.x, va.y);
      au.u[1] = pkbf(va.z, va.w);
      au.u[2] = pkbf(vb.x, vb.y);
      au.u[3] = pkbf(vb.z, vb.w);
      A[s] = au.v;
    }
    f32x4 acc[4];
#pragma unroll
    for (int t = 0; t < 4; ++t) {
      f32x4 z = {0.f, 0.f, 0.f, 0.f};
      z = __builtin_amdgcn_mfma_f32_16x16x32_bf16(A[0], B[t][0], z, 0, 0, 0);
      z = __builtin_amdgcn_mfma_f32_16x16x32_bf16(A[1], B[t][1], z, 0, 0, 0);
      z = __builtin_amdgcn_mfma_f32_16x16x32_bf16(A[2], B[t][2], z, 0, 0, 0);
      z = __builtin_amdgcn_mfma_f32_16x16x32_bf16(A[3], B[t][3], z, 0, 0, 0);
      acc[t] = z;
    }
#pragma unroll
    for (int r = 0; r < 4; ++r) {
      unsigned short* hp = h + (size_t)(n0 + g * 4 + r) * NF + 2 * lo;
      *(unsigned*)(hp)      = pkbf(acc[0][r], acc[1][r]);
      *(unsigned*)(hp + 32) = pkbf(acc[2][r], acc[3][r]);
    }
  }
}

// ---------------- edge-filter table ----------------
__global__ __launch_bounds__(256) void k_table(
    const float* __restrict__ w1, const float* __restrict__ b1,
    const float* __restrict__ w2, const float* __restrict__ b2,
    unsigned short* __restrict__ tab) {
  __shared__ float ssm[4][56];
  __shared__ float sh1[4][64];
  const int wave = threadIdx.x >> 6, lane = threadIdx.x & 63;
  const int wid = blockIdx.x * 4 + wave;
  const float b1v = b1[lane], b2v = b2[lane];
  for (int bin = wid; bin < NBIN; bin += 1024) {
    const float d = (float)bin * (F_CUTOFF / 16384.0f);
    if (lane < NG) {
      const float t0 = d - (float)lane * F_DELTA;
      ssm[wave][lane] = __expf(F_COEFF * t0 * t0);
    }
    float h1 = b1v;
#pragma unroll
    for (int gg = 0; gg < NG; ++gg)
      h1 = fmaf(ssm[wave][gg], w1[lane * NG + gg], h1);
    sh1[wave][lane] = fmaxf(h1, 0.f);
    float wv = b2v;
#pragma unroll
    for (int f = 0; f < NF; ++f)
      wv = fmaf(sh1[wave][f], w2[lane * NF + f], wv);
    const float C = 0.5f * (__cosf(d * (F_PI / F_CUTOFF)) + 1.0f);
    tab[(size_t)bin * NF + lane] = f2bf(wv * C);
  }
}

// ---------------- bucket histogram: 196 blocks x 1024 threads (r12/r14 proven) ----------------
__global__ __launch_bounds__(1024) void k_bhist(
    const int* __restrict__ ei, int* __restrict__ gcnt) {
  __shared__ int lcnt[NBKT];
  for (int i = threadIdx.x; i < NBKT; i += 1024) lcnt[i] = 0;
  __syncthreads();
  const int base = blockIdx.x * CHK;
  for (int i = threadIdx.x; i < CHK; i += 1024) {
    const int e = base + i;
    if (e < NEDGES) atomicAdd(&lcnt[ei[NEDGES + e] >> BSH], 1);
  }
  __syncthreads();
  for (int i = threadIdx.x; i < NBKT; i += 1024)
    if (lcnt[i]) atomicAdd(&gcnt[i], lcnt[i]);
}

// ---------------- bucket-scatter: 196 x 1024, reg-cached edges, packed 8B records ----------------
// k_bscan deleted (r19): each block computes the 196-element exclusive scan of gcnt locally
// (sboff), and reserves its chunk via sboff[bkt] + atomicAdd(relcur[bkt], lcnt) where relcur
// is zero-initialized. Placement semantics identical to r14's boff/bcur.
// record: x = src | (bin<<17)  (src<2^17, bin<=16384<2^15), y = dst
__global__ __launch_bounds__(1024) void k_bscatter(
    const int* __restrict__ ei, const float* __restrict__ ea,
    const int* __restrict__ gcnt, int* __restrict__ relcur,
    int2* __restrict__ spack) {
  __shared__ int lcnt[NBKT];
  __shared__ int lcur[NBKT];
  __shared__ int sboff[NBKT];
  __shared__ int sb[256];
  const int t = threadIdx.x;

  // local exclusive scan of gcnt (196 elems; first 256 threads do the ladder)
  if (t < 256) sb[t] = (t < NBKT) ? gcnt[t] : 0;
  __syncthreads();
  for (int off = 1; off < 256; off <<= 1) {
    int xv = 0;
    if (t < 256 && t >= off) xv = sb[t - off];
    __syncthreads();
    if (t < 256) sb[t] += xv;
    __syncthreads();
  }
  if (t < NBKT) sboff[t] = sb[t] - gcnt[t];
  if (t < NBKT) lcnt[t] = 0;
  __syncthreads();

  const int base = blockIdx.x * CHK;
  int dsts[8], srcs[8]; float eav[8];
#pragma unroll
  for (int k = 0; k < 8; ++k) {
    const int e = base + t + k * 1024;
    const bool v = e < NEDGES;
    dsts[k] = v ? ei[NEDGES + e] : -1;
    srcs[k] = v ? ei[e] : 0;
    eav[k]  = v ? ea[e] : 0.f;
    if (v) atomicAdd(&lcnt[dsts[k] >> BSH], 1);
  }
  __syncthreads();
  for (int i = t; i < NBKT; i += 1024)
    lcur[i] = lcnt[i] ? (sboff[i] + atomicAdd(&relcur[i], lcnt[i])) : 0;
  __syncthreads();
#pragma unroll
  for (int k = 0; k < 8; ++k) {
    if (dsts[k] >= 0) {
      const int pos = atomicAdd(&lcur[dsts[k] >> BSH], 1);
      const float dcl = fminf(fmaxf(eav[k], 0.f), F_CUTOFF);
      int bn = (int)(dcl * TSCALE + 0.5f);
      bn = (bn > 16384) ? 16384 : bn;
      int2 r; r.x = srcs[k] | (bn << 17); r.y = dsts[k];
      spack[pos] = r;
    }
  }
}

// ---------------- pass 2: per-bucket (512 nodes) LDS counting sort, 1024 threads ----------------
// s0/s1 recomputed from gcnt via local scan (k_bscan deleted).
__global__ __launch_bounds__(1024) void k_bsort(
    const int2* __restrict__ spack, const int* __restrict__ gcnt,
    int2* __restrict__ srec) {
  __shared__ int cnt[512];
  __shared__ int red[512];
  __shared__ int sb[256];
  __shared__ int ss0, ss1;
  const int b = blockIdx.x;
  const int t = threadIdx.x;

  if (t < 256) sb[t] = (t < NBKT) ? gcnt[t] : 0;
  __syncthreads();
  for (int off = 1; off < 256; off <<= 1) {
    int xv = 0;
    if (t < 256 && t >= off) xv = sb[t - off];
    __syncthreads();
    if (t < 256) sb[t] += xv;
    __syncthreads();
  }
  if (t == 0) { ss1 = sb[b]; ss0 = sb[b] - gcnt[b]; }
  if (t < 512) cnt[t] = 0;
  __syncthreads();
  const int s0 = ss0, s1 = ss1;
  const int nodeBase = b << BSH;

  for (int i = s0 + t; i < s1; i += 1024)
    atomicAdd(&cnt[spack[i].y - nodeBase], 1);
  __syncthreads();
  const int v = (t < 512) ? cnt[t] : 0;
  if (t < 512) red[t] = v;
  __syncthreads();
  for (int off = 1; off < 512; off <<= 1) {
    int xv = 0;
    if (t < 512 && t >= off) xv = red[t - off];
    __syncthreads();
    if (t < 512) red[t] += xv;
    __syncthreads();
  }
  if (t < 512) cnt[t] = s0 + red[t] - v;   // exclusive global base -> cursor
  __syncthreads();
  for (int i = s0 + t; i < s1; i += 1024) {
    const int2 r = spack[i];
    const int p = atomicAdd(&cnt[r.y - nodeBase], 1);
    srec[p] = r;
  }
}

// ---------------- kernel 2: table-lookup edge messages + carry-run flush (packed records) ----------------
// XCD swizzle: each XCD owns a contiguous dst span (agg atomic locality).
__global__ __launch_bounds__(256) void k_edge_tab(
    const int2* __restrict__ srec, const unsigned short* __restrict__ hbf,
    const unsigned* __restrict__ tab, unsigned short* __restrict__ agg) {
  const int wave = threadIdx.x >> 6, lane = threadIdx.x & 63;
  const int lo = lane & 15, g = lane >> 4;

  const int bid = blockIdx.x;
  const int bsw = (bid & 7) * 256 + (bid >> 3);   // 2048 blocks, 8 XCDs
  const int wid = bsw * 4 + wave;
  const int gbase = wid * EPW + g * EPG;          // even

  int run_dst = -1;
  float c0 = 0.f, c1 = 0.f, c2 = 0.f, c3 = 0.f;

  const int4* sp4 = (const int4*)srec;            // 2 records per int4
  int4 qa = sp4[gbase / 2];
  int4 qb = sp4[gbase / 2 + 1];

#pragma unroll 1
  for (int it = 0; it < EPG / 4; ++it) {
    const int eg = gbase + it * 4;
    const int4 ca = qa, cb = qb;
    {
      const int itn = (it + 1 < EPG / 4) ? it + 1 : it;
      const int egn = gbase + itn * 4;
      qa = sp4[egn / 2];
      qb = sp4[egn / 2 + 1];
    }

    const int px[4] = {ca.x, ca.z, cb.x, cb.z};
    const int py[4] = {ca.y, ca.w, cb.y, cb.w};
    int sv[4], dv[4], bnv[4];
#pragma unroll
    for (int r = 0; r < 4; ++r) {
      const bool val = (eg + r) < NEDGES;
      sv[r]  = val ? (px[r] & 0x1FFFF) : 0;
      bnv[r] = val ? ((unsigned)px[r] >> 17) : 0;
      dv[r]  = val ? py[r] : -1;
    }

    unsigned hp0[4], hp1[4];
#pragma unroll
    for (int r = 0; r < 4; ++r) {
      const unsigned short* hs = hbf + (size_t)sv[r] * NF + 2 * lo;
      hp0[r] = *(const unsigned*)(hs);
      hp1[r] = *(const unsigned*)(hs + 32);
    }
    unsigned tw0[4], tw1[4];
#pragma unroll
    for (int r = 0; r < 4; ++r) {
      const unsigned* trow = tab + (size_t)bnv[r] * (NF / 2);
      tw0[r] = trow[lo];
      tw1[r] = trow[16 + lo];
    }

#pragma unroll
    for (int r = 0; r < 4; ++r) {
      const float m0 = bf2f(hp0[r] & 0xffffu) * bf2f(tw0[r] & 0xffffu);
      const float m1 = bf2f(hp0[r] >> 16)     * bf2f(tw0[r] >> 16);
      const float m2 = bf2f(hp1[r] & 0xffffu) * bf2f(tw1[r] & 0xffffu);
      const float m3 = bf2f(hp1[r] >> 16)     * bf2f(tw1[r] >> 16);
      if (dv[r] != run_dst) {
        if (run_dst >= 0) {
          unsigned short* ap = agg + (size_t)run_dst * NF + 2 * lo;
          const unsigned k0 = pkbf(c0, c1), k1 = pkbf(c2, c3);
          asm volatile("global_atomic_pk_add_bf16 %0, %1, off" :: "v"(ap), "v"(k0));
          asm volatile("global_atomic_pk_add_bf16 %0, %1, off" :: "v"(ap + 32), "v"(k1));
        }
        c0 = 0.f; c1 = 0.f; c2 = 0.f; c3 = 0.f;
        run_dst = dv[r];
      }
      c0 += m0; c1 += m1; c2 += m2; c3 += m3;
    }
  }
  if (run_dst >= 0) {
    unsigned short* ap = agg + (size_t)run_dst * NF + 2 * lo;
    const unsigned k0 = pkbf(c0, c1), k1 = pkbf(c2, c3);
    asm volatile("global_atomic_pk_add_bf16 %0, %1, off" :: "v"(ap), "v"(k0));
    asm volatile("global_atomic_pk_add_bf16 %0, %1, off" :: "v"(ap + 32), "v"(k1));
  }
}

// ---------------- kernel 3: out[n][d] = x[n][d] + relu(b[d] + agg[n,:] . lin2_w[d,:]) ----------------
__global__ __launch_bounds__(256) void k_out(
    const float* __restrict__ x, const unsigned short* __restrict__ agg,
    const float* __restrict__ w2, const float* __restrict__ b,
    float* __restrict__ out) {
  __shared__ __align__(16) float sw[DIM][NF + 4];
  __shared__ __align__(16) float sa[4][4][NF];
  for (int i = threadIdx.x; i < DIM * NF; i += 256)
    sw[i >> 6][i & 63] = w2[i];
  __syncthreads();
  const int wave = threadIdx.x >> 6, lane = threadIdx.x & 63;
  const float bias0 = b[lane], bias1 = b[lane + 64];
  const int nIter = NNODES / 4;
  for (int it = blockIdx.x * 4 + wave; it < nIter; it += gridDim.x * 4) {
    const int n0 = it * 4;
#pragma unroll
    for (int i = 0; i < 4; ++i)
      sa[wave][i][lane] = bf2f((unsigned)agg[(size_t)(n0 + i) * NF + lane]);
    float acc[8];
#pragma unroll
    for (int i = 0; i < 4; ++i) { acc[2 * i] = bias0; acc[2 * i + 1] = bias1; }
#pragma unroll
    for (int j4 = 0; j4 < NF / 4; ++j4) {
      const float4 wv0 = *(const float4*)&sw[lane][j4 * 4];
      const float4 wv1 = *(const float4*)&sw[lane + 64][j4 * 4];
#pragma unroll
      for (int i = 0; i < 4; ++i) {
        const float4 av = *(const float4*)&sa[wave][i][j4 * 4];
        acc[2 * i]     = fmaf(wv0.x, av.x, acc[2 * i]);
        acc[2 * i]     = fmaf(wv0.y, av.y, acc[2 * i]);
        acc[2 * i]     = fmaf(wv0.z, av.z, acc[2 * i]);
        acc[2 * i]     = fmaf(wv0.w, av.w, acc[2 * i]);
        acc[2 * i + 1] = fmaf(wv1.x, av.x, acc[2 * i + 1]);
        acc[2 * i + 1] = fmaf(wv1.y, av.y, acc[2 * i + 1]);
        acc[2 * i + 1] = fmaf(wv1.z, av.z, acc[2 * i + 1]);
        acc[2 * i + 1] = fmaf(wv1.w, av.w, acc[2 * i + 1]);
      }
    }
#pragma unroll
    for (int i = 0; i < 4; ++i) {
      const size_t base = (size_t)(n0 + i) * DIM;
      out[base + lane]      = x[base + lane]      + fmaxf(acc[2 * i],     0.f);
      out[base + 64 + lane] = x[base + 64 + lane] + fmaxf(acc[2 * i + 1], 0.f);
    }
  }
}

extern "C" void kernel_launch(void* const* d_in, const int* in_sizes, int n_in,
                              void* d_out, int out_size, void* d_ws, size_t ws_size,
                              hipStream_t stream) {
  const float* x   = (const float*)d_in[0];
  const int*   ei  = (const int*)  d_in[1];
  const float* ea  = (const float*)d_in[3];   // edge_attr == edge_weight (same dist)
  const float* l1w = (const float*)d_in[4];
  const float* l2w = (const float*)d_in[5];
  const float* l2b = (const float*)d_in[6];
  const float* e1w = (const float*)d_in[7];
  const float* e1b = (const float*)d_in[8];
  const float* e2w = (const float*)d_in[9];
  const float* e2b = (const float*)d_in[10];
  float* out = (float*)d_out;

  // ws carve: hbf 12.8 + agg 12.8 + spack 12.8 + table 2.1 + gcnt/relcur ≈ 41 MB
  char* p = (char*)d_ws;
  unsigned short* hbf = (unsigned short*)p; p += (size_t)NNODES * NF * 2;
  unsigned short* agg = (unsigned short*)p; p += (size_t)NNODES * NF * 2;
  int2* spack = (int2*)p;                   p += (size_t)NEDGES * 8;
  unsigned short* tab = (unsigned short*)p; p += (size_t)16512 * NF * 2;
  int*  gcnt   = (int*)p;                   p += 1024 * 4;
  int*  relcur = (int*)p;                   p += 1024 * 4;

  // final sorted packed records (8B) live in d_out's dead space: EPTOT*8B = 13.6 MB < 51.2 MB
  int2* srec = (int2*)d_out;

  hipMemsetAsync(gcnt, 0, 2048 * sizeof(int), stream);   // zeroes gcnt AND relcur (adjacent)
  hipMemsetAsync(agg, 0, sizeof(unsigned short) * (size_t)NNODES * NF, stream);

  k_table    <<<256, 256, 0, stream>>>(e1w, e1b, e2w, e2b, tab);
  k_lin1_mfma<<<512, 256, 0, stream>>>(x, l1w, hbf);
  k_bhist    <<<NCHK, 1024, 0, stream>>>(ei, gcnt);
  k_bscatter <<<NCHK, 1024, 0, stream>>>(ei, ea, gcnt, relcur, spack);
  k_bsort    <<<NBKT, 1024, 0, stream>>>(spack, gcnt, srec);
  k_edge_tab <<<2048, 256, 0, stream>>>(srec, hbf, (const unsigned*)tab, agg);
  k_out      <<<2048, 256, 0, stream>>>(x, agg, l2w, l2b, out);
}

// Round 20
// 156.920 us; speedup vs baseline: 5.0935x; 1.0268x over previous
//
#include <hip/hip_runtime.h>
#include <hip/hip_bf16.h>

#define NNODES 100000
#define NEDGES 1600000
#define DIM    128
#define NF     64
#define NG     50
#define EPG    52        // edges per 16-lane group chunk (13 iters x 4)
#define EPW    208       // edges per wave (4 groups)
#define NWAVES 8192      // 2048 blocks x 4 waves
#define EPTOT  1703936   // NWAVES * EPW  (>= NEDGES, OOB slots masked)

#define BSH    9                           // bucket = dst >> 9 (512 nodes/bucket) — proven r10/r12/r14
#define NBKT   ((NNODES + 511) >> 9)       // 196 buckets
#define CHK    8192                        // bscatter edges/block (dense 42-edge chunks)
#define NCHK   ((NEDGES + CHK - 1) / CHK)  // 196 blocks

#define NBIN   16385                       // table rows: bin = round(d * 16384/5)

// fused aux kernel (table | bucket-hist): both branches VGPR/LDS-light (no MFMA -> r13 trap n/a)
#define TAB_BLOCKS 256
#define BH_CHK     2048
#define BH_BLOCKS  ((NEDGES + BH_CHK - 1) / BH_CHK)   // 782
#define AUX_BLOCKS (TAB_BLOCKS + BH_BLOCKS)           // 1038

constexpr float F_CUTOFF = 5.0f;
constexpr float F_DELTA  = F_CUTOFF / (NG - 1);
constexpr float F_COEFF  = -0.5f / (F_DELTA * F_DELTA);
constexpr float F_PI     = 3.14159265358979323846f;
constexpr float TSCALE   = 16384.0f / F_CUTOFF;

typedef __attribute__((ext_vector_type(8))) short short8v;
typedef __attribute__((ext_vector_type(4))) float f32x4;

__device__ inline unsigned short f2bf(float x) {
  __hip_bfloat16 h = __float2bfloat16(x);
  return *reinterpret_cast<unsigned short*>(&h);
}
__device__ inline unsigned pkbf(float a, float b) {
  float2 f2; f2.x = a; f2.y = b;
  __hip_bfloat162 h2 = __float22bfloat162_rn(f2);
  return *reinterpret_cast<unsigned*>(&h2);
}
__device__ inline float bf2f(unsigned int lo16) {
  return __uint_as_float(lo16 << 16);
}

// ---------------- kernel 1 (MFMA): h[n][f] = sum_k x[n][k] * lin1_w[f][k]  (bf16 out) ----------------
// launch_bounds(256,2): VGPR cap keeps the 64-VGPR B fragments resident (r6/r13 lesson).
// Also zeroes agg (r20): lin1 strictly precedes k_edge_tab in stream order, so the zeroing
// is visible before any atomic lands; removes a separate memset dispatch.
__global__ __launch_bounds__(256, 2) void k_lin1_mfma(
    const float* __restrict__ x, const float* __restrict__ w1,
    unsigned short* __restrict__ h, uint4* __restrict__ aggz) {
  const int wave = threadIdx.x >> 6, lane = threadIdx.x & 63;
  const int lo = lane & 15, g = lane >> 4;

  // ---- zero agg: 12.8 MB = 800000 x 16B
  {
    const uint4 z = {0u, 0u, 0u, 0u};
    const int tid = blockIdx.x * 256 + threadIdx.x;           // 131072 threads
    for (int i = tid; i < (NNODES * NF * 2) / 16; i += 512 * 256)
      aggz[i] = z;
  }

  short8v B[4][4];
#pragma unroll
  for (int t = 0; t < 4; ++t) {
    const int j = (t >> 1) * 32 + 2 * lo + (t & 1);
#pragma unroll
    for (int s = 0; s < 4; ++s) {
      union { short8v v; unsigned u[4]; } bu;
      const float* wr = w1 + j * DIM + s * 32 + g * 8;
#pragma unroll
      for (int p = 0; p < 4; ++p)
        bu.u[p] = pkbf(wr[2 * p], wr[2 * p + 1]);
      B[t][s] = bu.v;
    }
  }

  const int nIter = NNODES / 16;   // 6250
  for (int it = blockIdx.x * 4 + wave; it < nIter; it += gridDim.x * 4) {
    const int n0 = it * 16;
    short8v A[4];
#pragma unroll
    for (int s = 0; s < 4; ++s) {
      const float4 va = *(const float4*)&x[(size_t)(n0 + lo) * DIM + s * 32 + g * 8];
      const float4 vb = *(const float4*)&x[(size_t)(n0 + lo) * DIM + s * 32 + g * 8 + 4];
      union { short8v v; unsigned u[4]; } au;
      au.u[0] = pkbf(va.x, va.y);
      au.u[1] = pkbf(va.z, va.w);
      au.u[2] = pkbf(vb.x, vb.y);
      au.u[3] = pkbf(vb.z, vb.w);
      A[s] = au.v;
    }
    f32x4 acc[4];
#pragma unroll
    for (int t = 0; t < 4; ++t) {
      f32x4 z = {0.f, 0.f, 0.f, 0.f};
      z = __builtin_amdgcn_mfma_f32_16x16x32_bf16(A[0], B[t][0], z, 0, 0, 0);
      z = __builtin_amdgcn_mfma_f32_16x16x32_bf16(A[1], B[t][1], z, 0, 0, 0);
      z = __builtin_amdgcn_mfma_f32_16x16x32_bf16(A[2], B[t][2], z, 0, 0, 0);
      z = __builtin_amdgcn_mfma_f32_16x16x32_bf16(A[3], B[t][3], z, 0, 0, 0);
      acc[t] = z;
    }
#pragma unroll
    for (int r = 0; r < 4; ++r) {
      unsigned short* hp = h + (size_t)(n0 + g * 4 + r) * NF + 2 * lo;
      *(unsigned*)(hp)      = pkbf(acc[0][r], acc[1][r]);
      *(unsigned*)(hp + 32) = pkbf(acc[2][r], acc[3][r]);
    }
  }
}

// ---------------- fused aux: edge-filter table | bucket histogram ----------------
__global__ __launch_bounds__(256) void k_aux(
    const float* __restrict__ w1, const float* __restrict__ b1,
    const float* __restrict__ w2, const float* __restrict__ b2,
    unsigned short* __restrict__ tab,
    const int* __restrict__ ei, int* __restrict__ gcnt) {
  const int bid = blockIdx.x;
  if (bid < TAB_BLOCKS) {
    // ---- table branch: T[bin][j] = C(d)*(enn2(relu(enn1(smear(d))))+b2)
    __shared__ float ssm[4][56];
    __shared__ float sh1[4][64];
    const int wave = threadIdx.x >> 6, lane = threadIdx.x & 63;
    const int wid = bid * 4 + wave;
    const float b1v = b1[lane], b2v = b2[lane];
    for (int bin = wid; bin < NBIN; bin += TAB_BLOCKS * 4) {
      const float d = (float)bin * (F_CUTOFF / 16384.0f);
      if (lane < NG) {
        const float t0 = d - (float)lane * F_DELTA;
        ssm[wave][lane] = __expf(F_COEFF * t0 * t0);
      }
      float h1 = b1v;
#pragma unroll
      for (int gg = 0; gg < NG; ++gg)
        h1 = fmaf(ssm[wave][gg], w1[lane * NG + gg], h1);
      sh1[wave][lane] = fmaxf(h1, 0.f);
      float wv = b2v;
#pragma unroll
      for (int f = 0; f < NF; ++f)
        wv = fmaf(sh1[wave][f], w2[lane * NF + f], wv);
      const float C = 0.5f * (__cosf(d * (F_PI / F_CUTOFF)) + 1.0f);
      tab[(size_t)bin * NF + lane] = f2bf(wv * C);
    }
  } else {
    // ---- bucket-histogram branch (hist writes no records: chunk density n/a — r11 lesson)
    __shared__ int lcnt[NBKT];
    for (int i = threadIdx.x; i < NBKT; i += 256) lcnt[i] = 0;
    __syncthreads();
    const int base = (bid - TAB_BLOCKS) * BH_CHK;
    for (int i = threadIdx.x; i < BH_CHK; i += 256) {
      const int e = base + i;
      if (e < NEDGES) atomicAdd(&lcnt[ei[NEDGES + e] >> BSH], 1);
    }
    __syncthreads();
    for (int i = threadIdx.x; i < NBKT; i += 256)
      if (lcnt[i]) atomicAdd(&gcnt[i], lcnt[i]);
  }
}

// ---------------- bucket-scatter: 196 x 1024, reg-cached edges, packed 8B records ----------------
// In-kernel exclusive scan of gcnt (k_bscan deleted r19); chunk reservation via
// sboff[bkt] + atomicAdd(relcur[bkt], lcnt).  record: x = src | (bin<<17), y = dst
__global__ __launch_bounds__(1024) void k_bscatter(
    const int* __restrict__ ei, const float* __restrict__ ea,
    const int* __restrict__ gcnt, int* __restrict__ relcur,
    int2* __restrict__ spack) {
  __shared__ int lcnt[NBKT];
  __shared__ int lcur[NBKT];
  __shared__ int sboff[NBKT];
  __shared__ int sb[256];
  const int t = threadIdx.x;

  if (t < 256) sb[t] = (t < NBKT) ? gcnt[t] : 0;
  __syncthreads();
  for (int off = 1; off < 256; off <<= 1) {
    int xv = 0;
    if (t < 256 && t >= off) xv = sb[t - off];
    __syncthreads();
    if (t < 256) sb[t] += xv;
    __syncthreads();
  }
  if (t < NBKT) sboff[t] = sb[t] - gcnt[t];
  if (t < NBKT) lcnt[t] = 0;
  __syncthreads();

  const int base = blockIdx.x * CHK;
  int dsts[8], srcs[8]; float eav[8];
#pragma unroll
  for (int k = 0; k < 8; ++k) {
    const int e = base + t + k * 1024;
    const bool v = e < NEDGES;
    dsts[k] = v ? ei[NEDGES + e] : -1;
    srcs[k] = v ? ei[e] : 0;
    eav[k]  = v ? ea[e] : 0.f;
    if (v) atomicAdd(&lcnt[dsts[k] >> BSH], 1);
  }
  __syncthreads();
  for (int i = t; i < NBKT; i += 1024)
    lcur[i] = lcnt[i] ? (sboff[i] + atomicAdd(&relcur[i], lcnt[i])) : 0;
  __syncthreads();
#pragma unroll
  for (int k = 0; k < 8; ++k) {
    if (dsts[k] >= 0) {
      const int pos = atomicAdd(&lcur[dsts[k] >> BSH], 1);
      const float dcl = fminf(fmaxf(eav[k], 0.f), F_CUTOFF);
      int bn = (int)(dcl * TSCALE + 0.5f);
      bn = (bn > 16384) ? 16384 : bn;
      int2 r; r.x = srcs[k] | (bn << 17); r.y = dsts[k];
      spack[pos] = r;
    }
  }
}

// ---------------- pass 2: per-bucket (512 nodes) LDS counting sort, 1024 threads ----------------
__global__ __launch_bounds__(1024) void k_bsort(
    const int2* __restrict__ spack, const int* __restrict__ gcnt,
    int2* __restrict__ srec) {
  __shared__ int cnt[512];
  __shared__ int red[512];
  __shared__ int sb[256];
  __shared__ int ss0, ss1;
  const int b = blockIdx.x;
  const int t = threadIdx.x;

  if (t < 256) sb[t] = (t < NBKT) ? gcnt[t] : 0;
  __syncthreads();
  for (int off = 1; off < 256; off <<= 1) {
    int xv = 0;
    if (t < 256 && t >= off) xv = sb[t - off];
    __syncthreads();
    if (t < 256) sb[t] += xv;
    __syncthreads();
  }
  if (t == 0) { ss1 = sb[b]; ss0 = sb[b] - gcnt[b]; }
  if (t < 512) cnt[t] = 0;
  __syncthreads();
  const int s0 = ss0, s1 = ss1;
  const int nodeBase = b << BSH;

  for (int i = s0 + t; i < s1; i += 1024)
    atomicAdd(&cnt[spack[i].y - nodeBase], 1);
  __syncthreads();
  const int v = (t < 512) ? cnt[t] : 0;
  if (t < 512) red[t] = v;
  __syncthreads();
  for (int off = 1; off < 512; off <<= 1) {
    int xv = 0;
    if (t < 512 && t >= off) xv = red[t - off];
    __syncthreads();
    if (t < 512) red[t] += xv;
    __syncthreads();
  }
  if (t < 512) cnt[t] = s0 + red[t] - v;
  __syncthreads();
  for (int i = s0 + t; i < s1; i += 1024) {
    const int2 r = spack[i];
    const int p = atomicAdd(&cnt[r.y - nodeBase], 1);
    srec[p] = r;
  }
}

// ---------------- kernel 2: table-lookup edge messages + carry-run flush (packed records) ----------------
__global__ __launch_bounds__(256) void k_edge_tab(
    const int2* __restrict__ srec, const unsigned short* __restrict__ hbf,
    const unsigned* __restrict__ tab, unsigned short* __restrict__ agg) {
  const int wave = threadIdx.x >> 6, lane = threadIdx.x & 63;
  const int lo = lane & 15, g = lane >> 4;

  const int bid = blockIdx.x;
  const int bsw = (bid & 7) * 256 + (bid >> 3);   // XCD swizzle: contiguous dst span per XCD
  const int wid = bsw * 4 + wave;
  const int gbase = wid * EPW + g * EPG;

  int run_dst = -1;
  float c0 = 0.f, c1 = 0.f, c2 = 0.f, c3 = 0.f;

  const int4* sp4 = (const int4*)srec;
  int4 qa = sp4[gbase / 2];
  int4 qb = sp4[gbase / 2 + 1];

#pragma unroll 1
  for (int it = 0; it < EPG / 4; ++it) {
    const int eg = gbase + it * 4;
    const int4 ca = qa, cb = qb;
    {
      const int itn = (it + 1 < EPG / 4) ? it + 1 : it;
      const int egn = gbase + itn * 4;
      qa = sp4[egn / 2];
      qb = sp4[egn / 2 + 1];
    }

    const int px[4] = {ca.x, ca.z, cb.x, cb.z};
    const int py[4] = {ca.y, ca.w, cb.y, cb.w};
    int sv[4], dv[4], bnv[4];
#pragma unroll
    for (int r = 0; r < 4; ++r) {
      const bool val = (eg + r) < NEDGES;
      sv[r]  = val ? (px[r] & 0x1FFFF) : 0;
      bnv[r] = val ? ((unsigned)px[r] >> 17) : 0;
      dv[r]  = val ? py[r] : -1;
    }

    unsigned hp0[4], hp1[4];
#pragma unroll
    for (int r = 0; r < 4; ++r) {
      const unsigned short* hs = hbf + (size_t)sv[r] * NF + 2 * lo;
      hp0[r] = *(const unsigned*)(hs);
      hp1[r] = *(const unsigned*)(hs + 32);
    }
    unsigned tw0[4], tw1[4];
#pragma unroll
    for (int r = 0; r < 4; ++r) {
      const unsigned* trow = tab + (size_t)bnv[r] * (NF / 2);
      tw0[r] = trow[lo];
      tw1[r] = trow[16 + lo];
    }

#pragma unroll
    for (int r = 0; r < 4; ++r) {
      const float m0 = bf2f(hp0[r] & 0xffffu) * bf2f(tw0[r] & 0xffffu);
      const float m1 = bf2f(hp0[r] >> 16)     * bf2f(tw0[r] >> 16);
      const float m2 = bf2f(hp1[r] & 0xffffu) * bf2f(tw1[r] & 0xffffu);
      const float m3 = bf2f(hp1[r] >> 16)     * bf2f(tw1[r] >> 16);
      if (dv[r] != run_dst) {
        if (run_dst >= 0) {
          unsigned short* ap = agg + (size_t)run_dst * NF + 2 * lo;
          const unsigned k0 = pkbf(c0, c1), k1 = pkbf(c2, c3);
          asm volatile("global_atomic_pk_add_bf16 %0, %1, off" :: "v"(ap), "v"(k0));
          asm volatile("global_atomic_pk_add_bf16 %0, %1, off" :: "v"(ap + 32), "v"(k1));
        }
        c0 = 0.f; c1 = 0.f; c2 = 0.f; c3 = 0.f;
        run_dst = dv[r];
      }
      c0 += m0; c1 += m1; c2 += m2; c3 += m3;
    }
  }
  if (run_dst >= 0) {
    unsigned short* ap = agg + (size_t)run_dst * NF + 2 * lo;
    const unsigned k0 = pkbf(c0, c1), k1 = pkbf(c2, c3);
    asm volatile("global_atomic_pk_add_bf16 %0, %1, off" :: "v"(ap), "v"(k0));
    asm volatile("global_atomic_pk_add_bf16 %0, %1, off" :: "v"(ap + 32), "v"(k1));
  }
}

// ---------------- kernel 3: out[n][d] = x[n][d] + relu(b[d] + agg[n,:] . lin2_w[d,:]) ----------------
__global__ __launch_bounds__(256) void k_out(
    const float* __restrict__ x, const unsigned short* __restrict__ agg,
    const float* __restrict__ w2, const float* __restrict__ b,
    float* __restrict__ out) {
  __shared__ __align__(16) float sw[DIM][NF + 4];
  __shared__ __align__(16) float sa[4][4][NF];
  for (int i = threadIdx.x; i < DIM * NF; i += 256)
    sw[i >> 6][i & 63] = w2[i];
  __syncthreads();
  const int wave = threadIdx.x >> 6, lane = threadIdx.x & 63;
  const float bias0 = b[lane], bias1 = b[lane + 64];
  const int nIter = NNODES / 4;
  for (int it = blockIdx.x * 4 + wave; it < nIter; it += gridDim.x * 4) {
    const int n0 = it * 4;
#pragma unroll
    for (int i = 0; i < 4; ++i)
      sa[wave][i][lane] = bf2f((unsigned)agg[(size_t)(n0 + i) * NF + lane]);
    float acc[8];
#pragma unroll
    for (int i = 0; i < 4; ++i) { acc[2 * i] = bias0; acc[2 * i + 1] = bias1; }
#pragma unroll
    for (int j4 = 0; j4 < NF / 4; ++j4) {
      const float4 wv0 = *(const float4*)&sw[lane][j4 * 4];
      const float4 wv1 = *(const float4*)&sw[lane + 64][j4 * 4];
#pragma unroll
      for (int i = 0; i < 4; ++i) {
        const float4 av = *(const float4*)&sa[wave][i][j4 * 4];
        acc[2 * i]     = fmaf(wv0.x, av.x, acc[2 * i]);
        acc[2 * i]     = fmaf(wv0.y, av.y, acc[2 * i]);
        acc[2 * i]     = fmaf(wv0.z, av.z, acc[2 * i]);
        acc[2 * i]     = fmaf(wv0.w, av.w, acc[2 * i]);
        acc[2 * i + 1] = fmaf(wv1.x, av.x, acc[2 * i + 1]);
        acc[2 * i + 1] = fmaf(wv1.y, av.y, acc[2 * i + 1]);
        acc[2 * i + 1] = fmaf(wv1.z, av.z, acc[2 * i + 1]);
        acc[2 * i + 1] = fmaf(wv1.w, av.w, acc[2 * i + 1]);
      }
    }
#pragma unroll
    for (int i = 0; i < 4; ++i) {
      const size_t base = (size_t)(n0 + i) * DIM;
      out[base + lane]      = x[base + lane]      + fmaxf(acc[2 * i],     0.f);
      out[base + 64 + lane] = x[base + 64 + lane] + fmaxf(acc[2 * i + 1], 0.f);
    }
  }
}

extern "C" void kernel_launch(void* const* d_in, const int* in_sizes, int n_in,
                              void* d_out, int out_size, void* d_ws, size_t ws_size,
                              hipStream_t stream) {
  const float* x   = (const float*)d_in[0];
  const int*   ei  = (const int*)  d_in[1];
  const float* ea  = (const float*)d_in[3];   // edge_attr == edge_weight (same dist)
  const float* l1w = (const float*)d_in[4];
  const float* l2w = (const float*)d_in[5];
  const float* l2b = (const float*)d_in[6];
  const float* e1w = (const float*)d_in[7];
  const float* e1b = (const float*)d_in[8];
  const float* e2w = (const float*)d_in[9];
  const float* e2b = (const float*)d_in[10];
  float* out = (float*)d_out;

  // ws carve: hbf 12.8 + agg 12.8 + spack 12.8 + table 2.1 + gcnt/relcur ≈ 41 MB
  char* p = (char*)d_ws;
  unsigned short* hbf = (unsigned short*)p; p += (size_t)NNODES * NF * 2;
  unsigned short* agg = (unsigned short*)p; p += (size_t)NNODES * NF * 2;
  int2* spack = (int2*)p;                   p += (size_t)NEDGES * 8;
  unsigned short* tab = (unsigned short*)p; p += (size_t)16512 * NF * 2;
  int*  gcnt   = (int*)p;                   p += 1024 * 4;
  int*  relcur = (int*)p;                   p += 1024 * 4;

  // final sorted packed records (8B) live in d_out's dead space: EPTOT*8B = 13.6 MB < 51.2 MB
  int2* srec = (int2*)d_out;

  hipMemsetAsync(gcnt, 0, 2048 * sizeof(int), stream);   // zeroes gcnt AND relcur (adjacent)

  k_lin1_mfma<<<512, 256, 0, stream>>>(x, l1w, hbf, (uint4*)agg);
  k_aux      <<<AUX_BLOCKS, 256, 0, stream>>>(e1w, e1b, e2w, e2b, tab, ei, gcnt);
  k_bscatter <<<NCHK, 1024, 0, stream>>>(ei, ea, gcnt, relcur, spack);
  k_bsort    <<<NBKT, 1024, 0, stream>>>(spack, gcnt, srec);
  k_edge_tab <<<2048, 256, 0, stream>>>(srec, hbf, (const unsigned*)tab, agg);
  k_out      <<<2048, 256, 0, stream>>>(x, agg, l2w, l2b, out);
}